// Round 15
// baseline (126.732 us; speedup 1.0000x reference)
//
#include <hip/hip_runtime.h>
#include <math.h>

#define N_   16
#define C_   128
#define T_   150
#define V_   25
#define NH_  8
#define DK_  32
#define DV_  128
#define B_   400      // N_*V_
#define QO_  192      // 2*DK_+DV_
#define EPS_ 1e-5f

typedef __attribute__((ext_vector_type(4))) short bf16x4;
typedef __attribute__((ext_vector_type(4))) float f32x4;
typedef __attribute__((ext_vector_type(8))) short short8;

__device__ inline f32x4 mfma16(bf16x4 a, bf16x4 b, f32x4 c) {
#if __has_builtin(__builtin_amdgcn_mfma_f32_16x16x16bf16_1k)
  return __builtin_amdgcn_mfma_f32_16x16x16bf16_1k(a, b, c, 0, 0, 0);
#else
  asm volatile("v_mfma_f32_16x16x16_bf16 %0, %1, %2, %0"
               : "+v"(c) : "v"(a), "v"(b));
  return c;
#endif
}

__device__ inline short f2bf(float f) {            // RNE bf16
  union { float f; unsigned u; } v; v.f = f;
  unsigned u = v.u + 0x7fffu + ((v.u >> 16) & 1u);
  return (short)(u >> 16);
}
__device__ inline float lo16(unsigned u) { union { unsigned u; float f; } v; v.u = u << 16;        return v.f; }
__device__ inline float hi16(unsigned u) { union { unsigned u; float f; } v; v.u = u & 0xffff0000u; return v.f; }
__device__ inline unsigned pk2(float a, float b) { // fast-round pack 2xbf16
  union { float f; unsigned u; } x, y; x.f = a; y.f = b;
  return ((x.u + 0x8000u) >> 16) | ((y.u + 0x8000u) & 0xffff0000u);
}
// truncating pack 2xbf16 via one v_perm_b32 (lo=a, hi=b) — proven R6/R8
__device__ inline unsigned pktr(float a, float b) {
  union { float f; unsigned u; } x, y; x.f = a; y.f = b;
#if __has_builtin(__builtin_amdgcn_perm)
  return __builtin_amdgcn_perm(y.u, x.u, 0x07060302u);
#else
  return (x.u >> 16) | (y.u & 0xffff0000u);
#endif
}

// ---------------------------------------------------------------------------
// k_prep: bf16 weight copies + dBN folding + bf16 key_rel gather table
// ---------------------------------------------------------------------------
__global__ __launch_bounds__(256) void k_prep(
    const float* __restrict__ qkv_w, const float* __restrict__ attn_w,
    const float* __restrict__ dbn_g, const float* __restrict__ dbn_b,
    const float* __restrict__ dbn_m, const float* __restrict__ dbn_v,
    const float* __restrict__ key_rel,
    short* __restrict__ wqb, short* __restrict__ wab,
    short* __restrict__ krbg,
    float* __restrict__ dsc, float* __restrict__ dsh)
{
  const int tid = blockIdx.x*256 + threadIdx.x;
  const int nthr = gridDim.x*256;
  for (int i = tid; i < QO_*C_; i += nthr) wqb[i] = f2bf(qkv_w[i]);
  for (int i = tid; i < DV_*DV_; i += nthr) wab[i] = f2bf(attn_w[i]);
  for (int i = tid; i < 336*4; i += nthr) {   // bf16 kr table, row = m+16, guards
    int m = (i >> 2) - 16;
    krbg[i] = (m >= 0 && m < 2*T_-1) ? f2bf(key_rel[m*4 + (i & 3)]) : (short)0;
  }
  for (int i = tid; i < C_*V_; i += nthr) {
    float sc = dbn_g[i] * rsqrtf(dbn_v[i] + EPS_);
    dsc[i] = sc;
    dsh[i] = dbn_b[i] - dbn_m[i]*sc;
  }
}

// ---------------------------------------------------------------------------
// k_xt2: fused dBN + transpose  x[n][c][t][v] -> xtb[b=n*V+v][t][c] bf16
// write loop packs c-pairs into uint stores (half the store instructions)
// ---------------------------------------------------------------------------
__global__ __launch_bounds__(256) void k_xt2(
    const float* __restrict__ x, const float* __restrict__ dsc,
    const float* __restrict__ dsh, short* __restrict__ xtb)
{
  const int n = blockIdx.x, tv0 = blockIdx.y * 125;
  __shared__ short ls[C_][126];
  for (int i = threadIdx.x; i < C_*125; i += 256) {
    int c = i / 125, j = i % 125;
    int cv = c*V_ + j % 25;                  // tv0 % 25 == 0
    ls[c][j] = f2bf(x[((size_t)n*C_ + c)*(T_*V_) + tv0 + j] * dsc[cv] + dsh[cv]);
  }
  __syncthreads();
  for (int i = threadIdx.x; i < 125*64; i += 256) {
    int j = i >> 6, c2 = (i & 63) * 2;
    int tv = tv0 + j, t = tv / 25, v = tv % 25;
    unsigned u = (unsigned)(unsigned short)ls[c2][j]
               | ((unsigned)(unsigned short)ls[c2+1][j] << 16);
    *(unsigned*)&xtb[((size_t)(n*V_ + v)*T_ + t)*C_ + c2] = u;
  }
}

// ---------------------------------------------------------------------------
// k_qkv: bf16 MFMA GEMM. q channels (o<DK) pre-scaled by 0.5*log2e (R9-proven)
// ---------------------------------------------------------------------------
__global__ __launch_bounds__(256) void k_qkv(
    const short* __restrict__ xtb, const short* __restrict__ wqb,
    const float* __restrict__ qkv_b, short* __restrict__ qkvb)
{
  const int b = blockIdx.x, t0 = blockIdx.y * 80;
  __shared__ short xs[80][136];            // 272B rows: <=2-way banks
  for (int i = threadIdx.x; i < 80*16; i += 256) {
    int tt = i >> 4, ch = i & 15, t = t0 + tt;
    short8 vv = {0,0,0,0,0,0,0,0};
    if (t < T_) vv = *(const short8*)&xtb[((size_t)b*T_ + t)*C_ + ch*8];
    *(short8*)&xs[tt][ch*8] = vv;
  }
  __syncthreads();
  const int wave = threadIdx.x >> 6, lane = threadIdx.x & 63;
  const int tl = lane & 15, g = lane >> 4;
  const int ob = wave * 48;

  bf16x4 afr[3][8];
  #pragma unroll
  for (int mt = 0; mt < 3; ++mt)
    #pragma unroll
    for (int ks = 0; ks < 8; ++ks)
      afr[mt][ks] = *(const bf16x4*)&wqb[(ob + mt*16 + tl)*C_ + ks*16 + g*4];

  const f32x4 zero = {0.f,0.f,0.f,0.f};
  f32x4 acc[3][5];
  #pragma unroll
  for (int mt = 0; mt < 3; ++mt)
    #pragma unroll
    for (int nt = 0; nt < 5; ++nt) acc[mt][nt] = zero;

  #pragma unroll
  for (int ks = 0; ks < 8; ++ks) {
    bf16x4 bfr[5];
    #pragma unroll
    for (int nt = 0; nt < 5; ++nt)
      bfr[nt] = *(const bf16x4*)&xs[nt*16 + tl][ks*16 + g*4];
    #pragma unroll
    for (int mt = 0; mt < 3; ++mt)
      #pragma unroll
      for (int nt = 0; nt < 5; ++nt)
        acc[mt][nt] = mfma16(afr[mt][ks], bfr[nt], acc[mt][nt]);
  }

  float bia[3][4], scm[3];
  #pragma unroll
  for (int mt = 0; mt < 3; ++mt) {
    scm[mt] = (ob + mt*16 < DK_) ? (0.5f*1.44269504f) : 1.f;
    #pragma unroll
    for (int r = 0; r < 4; ++r) bia[mt][r] = qkv_b[ob + mt*16 + g*4 + r];
  }

  #pragma unroll
  for (int nt = 0; nt < 5; ++nt) {
    int tg = t0 + nt*16 + tl;
    if (tg >= T_) continue;
    #pragma unroll
    for (int mt = 0; mt < 3; ++mt) {
      int o = ob + mt*16 + g*4;
      short* dst = &qkvb[((size_t)b*QO_ + o)*T_ + tg];
      #pragma unroll
      for (int r = 0; r < 4; ++r)
        dst[r*T_] = f2bf((acc[mt][nt][r] + bia[mt][r]) * scm[mt]);
    }
  }
}

// ---------------------------------------------------------------------------
// k_attn: R14 structure at 512 threads / 8 waves: 10 t-tiles split tt=wave,
// tt+=8 -> critical path 2 tiles (vs 3 with 4 waves). Same grid (3200), same
// LDS, same per-block staging volume (spread over 8 waves). Lean staging,
// rel K=16 block-diagonal, no-max softmax, pktr, ones-MFMA denominator.
// ---------------------------------------------------------------------------
__global__ __launch_bounds__(512) void k_attn(
    const short* __restrict__ qkvb, const short* __restrict__ krbg,
    short* __restrict__ o2b)
{
  const int bh = blockIdx.x;          // 0..3199
  const int b  = bh >> 3, h = bh & 7;
  __shared__ short kbc[160*4];        // K[s][d<4]                (1280 B)
  __shared__ short qbc[160*4];        // Q[t][d<4] pre-scaled     (1280 B)
  __shared__ short ve[16][164];       // V^T[e][s]                (5248 B)
  __shared__ short krb[336*4];        // kr rows bf16x4, row m+16 (2688 B)
  const short* base = qkvb + (size_t)b*QO_*T_;
  const int tid = threadIdx.x;

  for (int i = tid; i < 320; i += 512) {      // K: 2 s per uint
    int d = i / 80, j = i % 80, s = 2*j;
    unsigned u = 0;
    if (j < 75) u = *(const unsigned*)&base[(DK_ + h*4 + d)*T_ + s];
    kbc[s*4 + d] = (short)u;
    kbc[(s+1)*4 + d] = (short)(u >> 16);
  }
  for (int i = tid; i < 320; i += 512) {      // Q: 2 t per uint
    int d = i / 80, j = i % 80, t = 2*j;
    unsigned u = 0;
    if (j < 75) u = *(const unsigned*)&base[(h*4 + d)*T_ + t];
    qbc[t*4 + d] = (short)u;
    qbc[(t+1)*4 + d] = (short)(u >> 16);
  }
  for (int i = tid; i < 1280; i += 512) {     // V^T: uint copy
    int e = i / 80, j = i % 80;
    unsigned u = 0;
    if (j < 75) u = *(const unsigned*)&base[(2*DK_ + h*16 + e)*T_ + 2*j];
    *(unsigned*)&ve[e][2*j] = u;
  }
  for (int i = tid; i < 672; i += 512)        // kr: uint copy of bf16 table
    *(unsigned*)&krb[2*i] = *(const unsigned*)&krbg[2*i];
  __syncthreads();

  const int wave = tid >> 6, lane = tid & 63;
  const int tl = lane & 15, g = lane >> 4, soff = g << 2;

  const bf16x4 zerob = {0, 0, 0, 0};
  const bf16x4 onesb = {(short)0x3F80, (short)0x3F80, (short)0x3F80, (short)0x3F80};
  const f32x4 zero = {0.f, 0.f, 0.f, 0.f};

  bf16x4 kfr[10], vfr[10];
  #pragma unroll
  for (int st = 0; st < 10; ++st) {
    kfr[st] = (g == 0) ? *(const bf16x4*)&kbc[(st*16 + tl)*4] : zerob;
    vfr[st] = *(const bf16x4*)&ve[tl][st*16 + soff];
  }

  const bool act = (g == (tl & 3));   // lane holds B' nonzeros only here
  const int kca = tl >> 2;            // ...and only in this K-chunk

  for (int tt = wave; tt < 10; tt += 8) {
    const int t0 = tt*16, tg = t0 + tl;
    union { unsigned u[2]; bf16x4 v; } bqu;
    bqu.v = *(const bf16x4*)&qbc[tg*4];       // q row (pre-scaled)
    const bf16x4 qfr = (g == 0) ? bqu.v : zerob;

    f32x4 c[10];
    #pragma unroll
    for (int st = 0; st < 10; ++st) c[st] = mfma16(kfr[st], qfr, zero);

    bf16x4 brel[4];
    #pragma unroll
    for (int kc = 0; kc < 4; ++kc)
      brel[kc] = (act && kc == kca) ? bqu.v : zerob;

    // A' gather base: row = (tl - g + 165 - t0) + st*16 - kc*4
    const bf16x4* krp = ((const bf16x4*)krb) + (tl - g + 165 - t0);
    #pragma unroll
    for (int st = 0; st < 10; ++st)
      #pragma unroll
      for (int kc = 0; kc < 4; ++kc)
        c[st] = mfma16(krp[st*16 - kc*4], brel[kc], c[st]);

    // mask padded s rows (s = 144 + soff + i >= 150): exp2(-3e38) -> 0
    #pragma unroll
    for (int i = 0; i < 4; ++i)
      if (soff + i >= 6) c[9][i] = -3.0e38f;

    f32x4 acc = zero, lacc = zero;
    #pragma unroll
    for (int st = 0; st < 10; ++st) {
      float p0 = __builtin_exp2f(c[st][0]);
      float p1 = __builtin_exp2f(c[st][1]);
      float p2 = __builtin_exp2f(c[st][2]);
      float p3 = __builtin_exp2f(c[st][3]);
      union { unsigned u[2]; bf16x4 v; } pf;
      pf.u[0] = pktr(p0, p1); pf.u[1] = pktr(p2, p3);
      acc  = mfma16(vfr[st], pf.v, acc);
      lacc = mfma16(onesb, pf.v, lacc);       // denominator on MFMA pipe
    }
    const float inv = __builtin_amdgcn_rcpf(lacc[0]);

    if (tg < T_) {
      unsigned u0 = pk2(acc[0]*inv, acc[1]*inv);
      unsigned u1 = pk2(acc[2]*inv, acc[3]*inv);
      *(uint2*)&o2b[((size_t)b*T_ + tg)*DV_ + h*16 + soff] = make_uint2(u0, u1);
    }
  }
}

// ---------------------------------------------------------------------------
// k_proj: bf16 MFMA GEMM  projb[b][o][t] = bf16(sum_c wab[o][c]*o2b[b][t][c] + attn_b[o])
// ---------------------------------------------------------------------------
__global__ __launch_bounds__(256) void k_proj(
    const short* __restrict__ o2b, const short* __restrict__ wab,
    const float* __restrict__ attn_b, short* __restrict__ projb)
{
  const int b = blockIdx.x, t0 = blockIdx.y * 80;
  __shared__ short xs[80][136];
  for (int i = threadIdx.x; i < 80*16; i += 256) {
    int tt = i >> 4, ch = i & 15, t = t0 + tt;
    short8 vv = {0,0,0,0,0,0,0,0};
    if (t < T_) vv = *(const short8*)&o2b[((size_t)b*T_ + t)*DV_ + ch*8];
    *(short8*)&xs[tt][ch*8] = vv;
  }
  __syncthreads();
  const int wave = threadIdx.x >> 6, lane = threadIdx.x & 63;
  const int tl = lane & 15, g = lane >> 4;
  const int ob = wave * 32;

  bf16x4 afr[2][8];
  #pragma unroll
  for (int mt = 0; mt < 2; ++mt)
    #pragma unroll
    for (int ks = 0; ks < 8; ++ks)
      afr[mt][ks] = *(const bf16x4*)&wab[(ob + mt*16 + tl)*DV_ + ks*16 + g*4];

  const f32x4 zero = {0.f,0.f,0.f,0.f};
  f32x4 acc[2][5];
  #pragma unroll
  for (int mt = 0; mt < 2; ++mt)
    #pragma unroll
    for (int nt = 0; nt < 5; ++nt) acc[mt][nt] = zero;

  #pragma unroll
  for (int ks = 0; ks < 8; ++ks) {
    bf16x4 bfr[5];
    #pragma unroll
    for (int nt = 0; nt < 5; ++nt)
      bfr[nt] = *(const bf16x4*)&xs[nt*16 + tl][ks*16 + g*4];
    #pragma unroll
    for (int mt = 0; mt < 2; ++mt)
      #pragma unroll
      for (int nt = 0; nt < 5; ++nt)
        acc[mt][nt] = mfma16(afr[mt][ks], bfr[nt], acc[mt][nt]);
  }

  float bia[2][4];
  #pragma unroll
  for (int mt = 0; mt < 2; ++mt)
    #pragma unroll
    for (int r = 0; r < 4; ++r) bia[mt][r] = attn_b[ob + mt*16 + g*4 + r];

  #pragma unroll
  for (int nt = 0; nt < 5; ++nt) {
    int tg = t0 + nt*16 + tl;
    if (tg >= T_) continue;
    #pragma unroll
    for (int mt = 0; mt < 2; ++mt) {
      int o = ob + mt*16 + g*4;
      short* dst = &projb[((size_t)b*DV_ + o)*T_ + tg];
      #pragma unroll
      for (int r = 0; r < 4; ++r)
        dst[r*T_] = f2bf(acc[mt][nt][r] + bia[mt][r]);
    }
  }
}

// ---------------------------------------------------------------------------
// k_final: transpose projb[b][o][t] -> out[n][o][t][v], + residual + BN + ReLU
// staging loop vectorized to uint copies (t-pairs, 4B aligned)
// ---------------------------------------------------------------------------
__global__ __launch_bounds__(256) void k_final(
    const short* __restrict__ projb, const float* __restrict__ x,
    const float* __restrict__ bn_g, const float* __restrict__ bn_b,
    const float* __restrict__ bn_m, const float* __restrict__ bn_v,
    float* __restrict__ out)
{
  const int n = blockIdx.x, o = blockIdx.y;
  __shared__ short ls[V_*T_];
  for (int i = threadIdx.x; i < V_*75; i += 256) {
    int v = i / 75, j = i % 75;
    *(unsigned*)&ls[v*T_ + 2*j] =
        *(const unsigned*)&projb[((size_t)(n*V_ + v)*DV_ + o)*T_ + 2*j];
  }
  __syncthreads();
  const float sc = bn_g[o] * rsqrtf(bn_v[o] + EPS_);
  const float sh = bn_b[o] - bn_m[o]*sc;
  const size_t base = ((size_t)n*C_ + o)*(T_*V_);
  for (int j = threadIdx.x; j < T_*V_; j += 256) {
    int t = j / V_, v = j % V_;
    float pv = lo16((unsigned)(unsigned short)ls[v*T_ + t]);
    float r = (pv + x[base + j]) * sc + sh;
    out[base + j] = fmaxf(r, 0.f);
  }
}

// ---------------------------------------------------------------------------
extern "C" void kernel_launch(void* const* d_in, const int* in_sizes, int n_in,
                              void* d_out, int out_size, void* d_ws, size_t ws_size,
                              hipStream_t stream) {
  const float* x       = (const float*)d_in[0];
  const float* qkv_w   = (const float*)d_in[1];
  const float* qkv_b   = (const float*)d_in[2];
  const float* key_rel = (const float*)d_in[3];
  const float* attn_w  = (const float*)d_in[4];
  const float* attn_b  = (const float*)d_in[5];
  const float* dbn_g   = (const float*)d_in[6];
  const float* dbn_b   = (const float*)d_in[7];
  const float* dbn_m   = (const float*)d_in[8];
  const float* dbn_v   = (const float*)d_in[9];
  const float* bn_g    = (const float*)d_in[10];
  const float* bn_b    = (const float*)d_in[11];
  const float* bn_m    = (const float*)d_in[12];
  const float* bn_v    = (const float*)d_in[13];

  // ws layout: xtb/o2b | qkvb | proj region (bf16 uses half) | consts
  short* xtb  = (short*)d_ws;                          // 7.68M shorts, reused as o2b
  short* o2b  = xtb;
  short* qkvb = xtb + (size_t)B_*C_*T_;                // 11.52M shorts
  float* projf = (float*)(qkvb + (size_t)B_*QO_*T_);   // region reserved as before
  short* projb = (short*)projf;                        // bf16 actually used
  float* dsc  = projf + (size_t)B_*DV_*T_;             // 3200
  float* dsh  = dsc + C_*V_;                           // 3200
  short* wqb  = (short*)(dsh + C_*V_);                 // 24576 shorts
  short* wab  = wqb + QO_*C_;                          // 16384 shorts
  short* krbg = wab + DV_*DV_;                         // 1344 shorts (bf16 kr)
  float* outp = (float*)d_out;

  k_prep<<<32, 256, 0, stream>>>(qkv_w, attn_w, dbn_g, dbn_b, dbn_m, dbn_v,
                                 key_rel, wqb, wab, krbg, dsc, dsh);
  k_xt2<<<dim3(N_, 30), 256, 0, stream>>>(x, dsc, dsh, xtb);
  k_qkv<<<dim3(B_, 2), 256, 0, stream>>>(xtb, wqb, qkv_b, qkvb);
  k_attn<<<dim3(B_*NH_), 512, 0, stream>>>(qkvb, krbg, o2b);
  k_proj<<<dim3(B_, 2), 256, 0, stream>>>(o2b, wab, attn_b, projb);
  k_final<<<dim3(N_, DV_), 256, 0, stream>>>(projb, x, bn_g, bn_b, bn_m, bn_v, outp);
}

// Round 16
// 122.710 us; speedup vs baseline: 1.0328x; 1.0328x over previous
//
#include <hip/hip_runtime.h>
#include <math.h>

#define N_   16
#define C_   128
#define T_   150
#define V_   25
#define NH_  8
#define DK_  32
#define DV_  128
#define B_   400      // N_*V_
#define QO_  192      // 2*DK_+DV_
#define EPS_ 1e-5f

typedef __attribute__((ext_vector_type(4))) short bf16x4;
typedef __attribute__((ext_vector_type(4))) float f32x4;
typedef __attribute__((ext_vector_type(8))) short short8;

__device__ inline f32x4 mfma16(bf16x4 a, bf16x4 b, f32x4 c) {
#if __has_builtin(__builtin_amdgcn_mfma_f32_16x16x16bf16_1k)
  return __builtin_amdgcn_mfma_f32_16x16x16bf16_1k(a, b, c, 0, 0, 0);
#else
  asm volatile("v_mfma_f32_16x16x16_bf16 %0, %1, %2, %0"
               : "+v"(c) : "v"(a), "v"(b));
  return c;
#endif
}

__device__ inline short f2bf(float f) {            // RNE bf16
  union { float f; unsigned u; } v; v.f = f;
  unsigned u = v.u + 0x7fffu + ((v.u >> 16) & 1u);
  return (short)(u >> 16);
}
__device__ inline float lo16(unsigned u) { union { unsigned u; float f; } v; v.u = u << 16;        return v.f; }
__device__ inline unsigned pk2(float a, float b) { // fast-round pack 2xbf16
  union { float f; unsigned u; } x, y; x.f = a; y.f = b;
  return ((x.u + 0x8000u) >> 16) | ((y.u + 0x8000u) & 0xffff0000u);
}
// truncating pack 2xbf16 via one v_perm_b32 (lo=a, hi=b) — proven R6/R8
__device__ inline unsigned pktr(float a, float b) {
  union { float f; unsigned u; } x, y; x.f = a; y.f = b;
#if __has_builtin(__builtin_amdgcn_perm)
  return __builtin_amdgcn_perm(y.u, x.u, 0x07060302u);
#else
  return (x.u >> 16) | (y.u & 0xffff0000u);
#endif
}

// ---------------------------------------------------------------------------
// k_prep: bf16 weight copies + dBN folding + bf16 key_rel gather table
// ---------------------------------------------------------------------------
__global__ __launch_bounds__(256) void k_prep(
    const float* __restrict__ qkv_w, const float* __restrict__ attn_w,
    const float* __restrict__ dbn_g, const float* __restrict__ dbn_b,
    const float* __restrict__ dbn_m, const float* __restrict__ dbn_v,
    const float* __restrict__ key_rel,
    short* __restrict__ wqb, short* __restrict__ wab,
    short* __restrict__ krbg,
    float* __restrict__ dsc, float* __restrict__ dsh)
{
  const int tid = blockIdx.x*256 + threadIdx.x;
  const int nthr = gridDim.x*256;
  for (int i = tid; i < QO_*C_; i += nthr) wqb[i] = f2bf(qkv_w[i]);
  for (int i = tid; i < DV_*DV_; i += nthr) wab[i] = f2bf(attn_w[i]);
  for (int i = tid; i < 336*4; i += nthr) {   // bf16 kr table, row = m+16, guards
    int m = (i >> 2) - 16;
    krbg[i] = (m >= 0 && m < 2*T_-1) ? f2bf(key_rel[m*4 + (i & 3)]) : (short)0;
  }
  for (int i = tid; i < C_*V_; i += nthr) {
    float sc = dbn_g[i] * rsqrtf(dbn_v[i] + EPS_);
    dsc[i] = sc;
    dsh[i] = dbn_b[i] - dbn_m[i]*sc;
  }
}

// ---------------------------------------------------------------------------
// k_xt2: fused dBN + transpose  x[n][c][t][v] -> xtb[b=n*V+v][t][c] bf16
// write loop packs c-pairs into uint stores (half the store instructions)
// ---------------------------------------------------------------------------
__global__ __launch_bounds__(256) void k_xt2(
    const float* __restrict__ x, const float* __restrict__ dsc,
    const float* __restrict__ dsh, short* __restrict__ xtb)
{
  const int n = blockIdx.x, tv0 = blockIdx.y * 125;
  __shared__ short ls[C_][126];
  for (int i = threadIdx.x; i < C_*125; i += 256) {
    int c = i / 125, j = i % 125;
    int cv = c*V_ + j % 25;                  // tv0 % 25 == 0
    ls[c][j] = f2bf(x[((size_t)n*C_ + c)*(T_*V_) + tv0 + j] * dsc[cv] + dsh[cv]);
  }
  __syncthreads();
  for (int i = threadIdx.x; i < 125*64; i += 256) {
    int j = i >> 6, c2 = (i & 63) * 2;
    int tv = tv0 + j, t = tv / 25, v = tv % 25;
    unsigned u = (unsigned)(unsigned short)ls[c2][j]
               | ((unsigned)(unsigned short)ls[c2+1][j] << 16);
    *(unsigned*)&xtb[((size_t)(n*V_ + v)*T_ + t)*C_ + c2] = u;
  }
}

// ---------------------------------------------------------------------------
// k_qkv: bf16 MFMA GEMM. q channels (o<DK) pre-scaled by 0.5*log2e (R9-proven)
// ---------------------------------------------------------------------------
__global__ __launch_bounds__(256) void k_qkv(
    const short* __restrict__ xtb, const short* __restrict__ wqb,
    const float* __restrict__ qkv_b, short* __restrict__ qkvb)
{
  const int b = blockIdx.x, t0 = blockIdx.y * 80;
  __shared__ short xs[80][136];            // 272B rows: <=2-way banks
  for (int i = threadIdx.x; i < 80*16; i += 256) {
    int tt = i >> 4, ch = i & 15, t = t0 + tt;
    short8 vv = {0,0,0,0,0,0,0,0};
    if (t < T_) vv = *(const short8*)&xtb[((size_t)b*T_ + t)*C_ + ch*8];
    *(short8*)&xs[tt][ch*8] = vv;
  }
  __syncthreads();
  const int wave = threadIdx.x >> 6, lane = threadIdx.x & 63;
  const int tl = lane & 15, g = lane >> 4;
  const int ob = wave * 48;

  bf16x4 afr[3][8];
  #pragma unroll
  for (int mt = 0; mt < 3; ++mt)
    #pragma unroll
    for (int ks = 0; ks < 8; ++ks)
      afr[mt][ks] = *(const bf16x4*)&wqb[(ob + mt*16 + tl)*C_ + ks*16 + g*4];

  const f32x4 zero = {0.f,0.f,0.f,0.f};
  f32x4 acc[3][5];
  #pragma unroll
  for (int mt = 0; mt < 3; ++mt)
    #pragma unroll
    for (int nt = 0; nt < 5; ++nt) acc[mt][nt] = zero;

  #pragma unroll
  for (int ks = 0; ks < 8; ++ks) {
    bf16x4 bfr[5];
    #pragma unroll
    for (int nt = 0; nt < 5; ++nt)
      bfr[nt] = *(const bf16x4*)&xs[nt*16 + tl][ks*16 + g*4];
    #pragma unroll
    for (int mt = 0; mt < 3; ++mt)
      #pragma unroll
      for (int nt = 0; nt < 5; ++nt)
        acc[mt][nt] = mfma16(afr[mt][ks], bfr[nt], acc[mt][nt]);
  }

  float bia[3][4], scm[3];
  #pragma unroll
  for (int mt = 0; mt < 3; ++mt) {
    scm[mt] = (ob + mt*16 < DK_) ? (0.5f*1.44269504f) : 1.f;
    #pragma unroll
    for (int r = 0; r < 4; ++r) bia[mt][r] = qkv_b[ob + mt*16 + g*4 + r];
  }

  #pragma unroll
  for (int nt = 0; nt < 5; ++nt) {
    int tg = t0 + nt*16 + tl;
    if (tg >= T_) continue;
    #pragma unroll
    for (int mt = 0; mt < 3; ++mt) {
      int o = ob + mt*16 + g*4;
      short* dst = &qkvb[((size_t)b*QO_ + o)*T_ + tg];
      #pragma unroll
      for (int r = 0; r < 4; ++r)
        dst[r*T_] = f2bf((acc[mt][nt][r] + bia[mt][r]) * scm[mt]);
    }
  }
}

// ---------------------------------------------------------------------------
// k_attn: R14-proven (4 waves, lean staging, rel K=16 block-diagonal MFMA,
// no-max softmax, pktr packing, ones-MFMA denominator). K/Q staging merged
// into one uniform loop. Balance fixes abandoned (4 failed attempts — with
// ~12 waves/CU the scheduler already fills intra-block idle slots).
// ---------------------------------------------------------------------------
__global__ __launch_bounds__(256) void k_attn(
    const short* __restrict__ qkvb, const short* __restrict__ krbg,
    short* __restrict__ o2b)
{
  const int bh = blockIdx.x;          // 0..3199
  const int b  = bh >> 3, h = bh & 7;
  __shared__ short kbc[160*4];        // K[s][d<4]                (1280 B)
  __shared__ short qbc[160*4];        // Q[t][d<4] pre-scaled     (1280 B)
  __shared__ short ve[16][164];       // V^T[e][s]                (5248 B)
  __shared__ short krb[336*4];        // kr rows bf16x4, row m+16 (2688 B)
  const short* base = qkvb + (size_t)b*QO_*T_;
  const int tid = threadIdx.x;

  for (int i = tid; i < 640; i += 256) {      // K then Q: 2 s/t per uint
    int isq = i >= 320, r = i - isq*320;
    int d = r / 80, j = r - d*80, s = 2*j;
    unsigned u = 0;
    if (j < 75) u = *(const unsigned*)&base[((isq ? 0 : DK_) + h*4 + d)*T_ + s];
    short* dst = isq ? qbc : kbc;
    dst[s*4 + d] = (short)u;
    dst[(s+1)*4 + d] = (short)(u >> 16);
  }
  for (int i = tid; i < 1280; i += 256) {     // V^T: uint copy
    int e = i / 80, j = i % 80;
    unsigned u = 0;
    if (j < 75) u = *(const unsigned*)&base[(2*DK_ + h*16 + e)*T_ + 2*j];
    *(unsigned*)&ve[e][2*j] = u;
  }
  for (int i = tid; i < 672; i += 256)        // kr: uint copy of bf16 table
    *(unsigned*)&krb[2*i] = *(const unsigned*)&krbg[2*i];
  __syncthreads();

  const int wave = tid >> 6, lane = tid & 63;
  const int tl = lane & 15, g = lane >> 4, soff = g << 2;

  const bf16x4 zerob = {0, 0, 0, 0};
  const bf16x4 onesb = {(short)0x3F80, (short)0x3F80, (short)0x3F80, (short)0x3F80};
  const f32x4 zero = {0.f, 0.f, 0.f, 0.f};

  bf16x4 kfr[10], vfr[10];
  #pragma unroll
  for (int st = 0; st < 10; ++st) {
    kfr[st] = (g == 0) ? *(const bf16x4*)&kbc[(st*16 + tl)*4] : zerob;
    vfr[st] = *(const bf16x4*)&ve[tl][st*16 + soff];
  }

  const bool act = (g == (tl & 3));   // lane holds B' nonzeros only here
  const int kca = tl >> 2;            // ...and only in this K-chunk

  for (int tt = wave; tt < 10; tt += 4) {
    const int t0 = tt*16, tg = t0 + tl;
    union { unsigned u[2]; bf16x4 v; } bqu;
    bqu.v = *(const bf16x4*)&qbc[tg*4];       // q row (pre-scaled)
    const bf16x4 qfr = (g == 0) ? bqu.v : zerob;

    f32x4 c[10];
    #pragma unroll
    for (int st = 0; st < 10; ++st) c[st] = mfma16(kfr[st], qfr, zero);

    bf16x4 brel[4];
    #pragma unroll
    for (int kc = 0; kc < 4; ++kc)
      brel[kc] = (act && kc == kca) ? bqu.v : zerob;

    // A' gather base: row = (tl - g + 165 - t0) + st*16 - kc*4
    const bf16x4* krp = ((const bf16x4*)krb) + (tl - g + 165 - t0);
    #pragma unroll
    for (int st = 0; st < 10; ++st)
      #pragma unroll
      for (int kc = 0; kc < 4; ++kc)
        c[st] = mfma16(krp[st*16 - kc*4], brel[kc], c[st]);

    // mask padded s rows (s = 144 + soff + i >= 150): exp2(-3e38) -> 0
    #pragma unroll
    for (int i = 0; i < 4; ++i)
      if (soff + i >= 6) c[9][i] = -3.0e38f;

    f32x4 acc = zero, lacc = zero;
    #pragma unroll
    for (int st = 0; st < 10; ++st) {
      float p0 = __builtin_exp2f(c[st][0]);
      float p1 = __builtin_exp2f(c[st][1]);
      float p2 = __builtin_exp2f(c[st][2]);
      float p3 = __builtin_exp2f(c[st][3]);
      union { unsigned u[2]; bf16x4 v; } pf;
      pf.u[0] = pktr(p0, p1); pf.u[1] = pktr(p2, p3);
      acc  = mfma16(vfr[st], pf.v, acc);
      lacc = mfma16(onesb, pf.v, lacc);       // denominator on MFMA pipe
    }
    const float inv = __builtin_amdgcn_rcpf(lacc[0]);

    if (tg < T_) {
      unsigned u0 = pk2(acc[0]*inv, acc[1]*inv);
      unsigned u1 = pk2(acc[2]*inv, acc[3]*inv);
      *(uint2*)&o2b[((size_t)b*T_ + tg)*DV_ + h*16 + soff] = make_uint2(u0, u1);
    }
  }
}

// ---------------------------------------------------------------------------
// k_proj: bf16 MFMA GEMM  projb[b][o][t] = bf16(sum_c wab[o][c]*o2b[b][t][c] + attn_b[o])
// ---------------------------------------------------------------------------
__global__ __launch_bounds__(256) void k_proj(
    const short* __restrict__ o2b, const short* __restrict__ wab,
    const float* __restrict__ attn_b, short* __restrict__ projb)
{
  const int b = blockIdx.x, t0 = blockIdx.y * 80;
  __shared__ short xs[80][136];
  for (int i = threadIdx.x; i < 80*16; i += 256) {
    int tt = i >> 4, ch = i & 15, t = t0 + tt;
    short8 vv = {0,0,0,0,0,0,0,0};
    if (t < T_) vv = *(const short8*)&o2b[((size_t)b*T_ + t)*DV_ + ch*8];
    *(short8*)&xs[tt][ch*8] = vv;
  }
  __syncthreads();
  const int wave = threadIdx.x >> 6, lane = threadIdx.x & 63;
  const int tl = lane & 15, g = lane >> 4;
  const int ob = wave * 32;

  bf16x4 afr[2][8];
  #pragma unroll
  for (int mt = 0; mt < 2; ++mt)
    #pragma unroll
    for (int ks = 0; ks < 8; ++ks)
      afr[mt][ks] = *(const bf16x4*)&wab[(ob + mt*16 + tl)*DV_ + ks*16 + g*4];

  const f32x4 zero = {0.f,0.f,0.f,0.f};
  f32x4 acc[2][5];
  #pragma unroll
  for (int mt = 0; mt < 2; ++mt)
    #pragma unroll
    for (int nt = 0; nt < 5; ++nt) acc[mt][nt] = zero;

  #pragma unroll
  for (int ks = 0; ks < 8; ++ks) {
    bf16x4 bfr[5];
    #pragma unroll
    for (int nt = 0; nt < 5; ++nt)
      bfr[nt] = *(const bf16x4*)&xs[nt*16 + tl][ks*16 + g*4];
    #pragma unroll
    for (int mt = 0; mt < 2; ++mt)
      #pragma unroll
      for (int nt = 0; nt < 5; ++nt)
        acc[mt][nt] = mfma16(afr[mt][ks], bfr[nt], acc[mt][nt]);
  }

  float bia[2][4];
  #pragma unroll
  for (int mt = 0; mt < 2; ++mt)
    #pragma unroll
    for (int r = 0; r < 4; ++r) bia[mt][r] = attn_b[ob + mt*16 + g*4 + r];

  #pragma unroll
  for (int nt = 0; nt < 5; ++nt) {
    int tg = t0 + nt*16 + tl;
    if (tg >= T_) continue;
    #pragma unroll
    for (int mt = 0; mt < 2; ++mt) {
      int o = ob + mt*16 + g*4;
      short* dst = &projb[((size_t)b*DV_ + o)*T_ + tg];
      #pragma unroll
      for (int r = 0; r < 4; ++r)
        dst[r*T_] = f2bf(acc[mt][nt][r] + bia[mt][r]);
    }
  }
}

// ---------------------------------------------------------------------------
// k_final: transpose projb[b][o][t] -> out[n][o][t][v], + residual + BN + ReLU
// staging loop vectorized to uint copies (t-pairs, 4B aligned)
// ---------------------------------------------------------------------------
__global__ __launch_bounds__(256) void k_final(
    const short* __restrict__ projb, const float* __restrict__ x,
    const float* __restrict__ bn_g, const float* __restrict__ bn_b,
    const float* __restrict__ bn_m, const float* __restrict__ bn_v,
    float* __restrict__ out)
{
  const int n = blockIdx.x, o = blockIdx.y;
  __shared__ short ls[V_*T_];
  for (int i = threadIdx.x; i < V_*75; i += 256) {
    int v = i / 75, j = i % 75;
    *(unsigned*)&ls[v*T_ + 2*j] =
        *(const unsigned*)&projb[((size_t)(n*V_ + v)*DV_ + o)*T_ + 2*j];
  }
  __syncthreads();
  const float sc = bn_g[o] * rsqrtf(bn_v[o] + EPS_);
  const float sh = bn_b[o] - bn_m[o]*sc;
  const size_t base = ((size_t)n*C_ + o)*(T_*V_);
  for (int j = threadIdx.x; j < T_*V_; j += 256) {
    int t = j / V_, v = j % V_;
    float pv = lo16((unsigned)(unsigned short)ls[v*T_ + t]);
    float r = (pv + x[base + j]) * sc + sh;
    out[base + j] = fmaxf(r, 0.f);
  }
}

// ---------------------------------------------------------------------------
extern "C" void kernel_launch(void* const* d_in, const int* in_sizes, int n_in,
                              void* d_out, int out_size, void* d_ws, size_t ws_size,
                              hipStream_t stream) {
  const float* x       = (const float*)d_in[0];
  const float* qkv_w   = (const float*)d_in[1];
  const float* qkv_b   = (const float*)d_in[2];
  const float* key_rel = (const float*)d_in[3];
  const float* attn_w  = (const float*)d_in[4];
  const float* attn_b  = (const float*)d_in[5];
  const float* dbn_g   = (const float*)d_in[6];
  const float* dbn_b   = (const float*)d_in[7];
  const float* dbn_m   = (const float*)d_in[8];
  const float* dbn_v   = (const float*)d_in[9];
  const float* bn_g    = (const float*)d_in[10];
  const float* bn_b    = (const float*)d_in[11];
  const float* bn_m    = (const float*)d_in[12];
  const float* bn_v    = (const float*)d_in[13];

  // ws layout: xtb/o2b | qkvb | proj region (bf16 uses half) | consts
  short* xtb  = (short*)d_ws;                          // 7.68M shorts, reused as o2b
  short* o2b  = xtb;
  short* qkvb = xtb + (size_t)B_*C_*T_;                // 11.52M shorts
  float* projf = (float*)(qkvb + (size_t)B_*QO_*T_);   // region reserved as before
  short* projb = (short*)projf;                        // bf16 actually used
  float* dsc  = projf + (size_t)B_*DV_*T_;             // 3200
  float* dsh  = dsc + C_*V_;                           // 3200
  short* wqb  = (short*)(dsh + C_*V_);                 // 24576 shorts
  short* wab  = wqb + QO_*C_;                          // 16384 shorts
  short* krbg = wab + DV_*DV_;                         // 1344 shorts (bf16 kr)
  float* outp = (float*)d_out;

  k_prep<<<32, 256, 0, stream>>>(qkv_w, attn_w, dbn_g, dbn_b, dbn_m, dbn_v,
                                 key_rel, wqb, wab, krbg, dsc, dsh);
  k_xt2<<<dim3(N_, 30), 256, 0, stream>>>(x, dsc, dsh, xtb);
  k_qkv<<<dim3(B_, 2), 256, 0, stream>>>(xtb, wqb, qkv_b, qkvb);
  k_attn<<<dim3(B_*NH_), 256, 0, stream>>>(qkvb, krbg, o2b);
  k_proj<<<dim3(B_, 2), 256, 0, stream>>>(o2b, wab, attn_b, projb);
  k_final<<<dim3(N_, DV_), 256, 0, stream>>>(projb, x, bn_g, bn_b, bn_m, bn_v, outp);
}

// Round 17
// 119.472 us; speedup vs baseline: 1.0608x; 1.0271x over previous
//
#include <hip/hip_runtime.h>
#include <math.h>

#define N_   16
#define C_   128
#define T_   150
#define V_   25
#define NH_  8
#define DK_  32
#define DV_  128
#define B_   400      // N_*V_
#define QO_  192      // 2*DK_+DV_
#define EPS_ 1e-5f

typedef __attribute__((ext_vector_type(4))) short bf16x4;
typedef __attribute__((ext_vector_type(4))) float f32x4;
typedef __attribute__((ext_vector_type(8))) short short8;

__device__ inline f32x4 mfma16(bf16x4 a, bf16x4 b, f32x4 c) {
#if __has_builtin(__builtin_amdgcn_mfma_f32_16x16x16bf16_1k)
  return __builtin_amdgcn_mfma_f32_16x16x16bf16_1k(a, b, c, 0, 0, 0);
#else
  asm volatile("v_mfma_f32_16x16x16_bf16 %0, %1, %2, %0"
               : "+v"(c) : "v"(a), "v"(b));
  return c;
#endif
}

__device__ inline short f2bf(float f) {            // RNE bf16
  union { float f; unsigned u; } v; v.f = f;
  unsigned u = v.u + 0x7fffu + ((v.u >> 16) & 1u);
  return (short)(u >> 16);
}
__device__ inline float lo16(unsigned u) { union { unsigned u; float f; } v; v.u = u << 16;        return v.f; }
__device__ inline unsigned pk2(float a, float b) { // fast-round pack 2xbf16
  union { float f; unsigned u; } x, y; x.f = a; y.f = b;
  return ((x.u + 0x8000u) >> 16) | ((y.u + 0x8000u) & 0xffff0000u);
}
// truncating pack 2xbf16 via one v_perm_b32 (lo=a, hi=b) — proven R6/R8
__device__ inline unsigned pktr(float a, float b) {
  union { float f; unsigned u; } x, y; x.f = a; y.f = b;
#if __has_builtin(__builtin_amdgcn_perm)
  return __builtin_amdgcn_perm(y.u, x.u, 0x07060302u);
#else
  return (x.u >> 16) | (y.u & 0xffff0000u);
#endif
}

// ---------------------------------------------------------------------------
// k_prep: bf16 weight copies + dBN folding + bf16 key_rel gather table
// ---------------------------------------------------------------------------
__global__ __launch_bounds__(256) void k_prep(
    const float* __restrict__ qkv_w, const float* __restrict__ attn_w,
    const float* __restrict__ dbn_g, const float* __restrict__ dbn_b,
    const float* __restrict__ dbn_m, const float* __restrict__ dbn_v,
    const float* __restrict__ key_rel,
    short* __restrict__ wqb, short* __restrict__ wab,
    short* __restrict__ krbg,
    float* __restrict__ dsc, float* __restrict__ dsh)
{
  const int tid = blockIdx.x*256 + threadIdx.x;
  const int nthr = gridDim.x*256;
  for (int i = tid; i < QO_*C_; i += nthr) wqb[i] = f2bf(qkv_w[i]);
  for (int i = tid; i < DV_*DV_; i += nthr) wab[i] = f2bf(attn_w[i]);
  for (int i = tid; i < 336*4; i += nthr) {   // bf16 kr table, row = m+16, guards
    int m = (i >> 2) - 16;
    krbg[i] = (m >= 0 && m < 2*T_-1) ? f2bf(key_rel[m*4 + (i & 3)]) : (short)0;
  }
  for (int i = tid; i < C_*V_; i += nthr) {
    float sc = dbn_g[i] * rsqrtf(dbn_v[i] + EPS_);
    dsc[i] = sc;
    dsh[i] = dbn_b[i] - dbn_m[i]*sc;
  }
}

// ---------------------------------------------------------------------------
// k_xt2: fused dBN + transpose  x[n][c][t][v] -> xtb[b=n*V+v][t][c] bf16
// write loop packs c-pairs into uint stores (half the store instructions)
// ---------------------------------------------------------------------------
__global__ __launch_bounds__(256) void k_xt2(
    const float* __restrict__ x, const float* __restrict__ dsc,
    const float* __restrict__ dsh, short* __restrict__ xtb)
{
  const int n = blockIdx.x, tv0 = blockIdx.y * 125;
  __shared__ short ls[C_][126];
  for (int i = threadIdx.x; i < C_*125; i += 256) {
    int c = i / 125, j = i % 125;
    int cv = c*V_ + j % 25;                  // tv0 % 25 == 0
    ls[c][j] = f2bf(x[((size_t)n*C_ + c)*(T_*V_) + tv0 + j] * dsc[cv] + dsh[cv]);
  }
  __syncthreads();
  for (int i = threadIdx.x; i < 125*64; i += 256) {
    int j = i >> 6, c2 = (i & 63) * 2;
    int tv = tv0 + j, t = tv / 25, v = tv % 25;
    unsigned u = (unsigned)(unsigned short)ls[c2][j]
               | ((unsigned)(unsigned short)ls[c2+1][j] << 16);
    *(unsigned*)&xtb[((size_t)(n*V_ + v)*T_ + t)*C_ + c2] = u;
  }
}

// ---------------------------------------------------------------------------
// k_qkv: bf16 MFMA GEMM. q channels (o<DK) pre-scaled by 0.5*log2e (R9-proven)
// ---------------------------------------------------------------------------
__global__ __launch_bounds__(256) void k_qkv(
    const short* __restrict__ xtb, const short* __restrict__ wqb,
    const float* __restrict__ qkv_b, short* __restrict__ qkvb)
{
  const int b = blockIdx.x, t0 = blockIdx.y * 80;
  __shared__ short xs[80][136];            // 272B rows: <=2-way banks
  for (int i = threadIdx.x; i < 80*16; i += 256) {
    int tt = i >> 4, ch = i & 15, t = t0 + tt;
    short8 vv = {0,0,0,0,0,0,0,0};
    if (t < T_) vv = *(const short8*)&xtb[((size_t)b*T_ + t)*C_ + ch*8];
    *(short8*)&xs[tt][ch*8] = vv;
  }
  __syncthreads();
  const int wave = threadIdx.x >> 6, lane = threadIdx.x & 63;
  const int tl = lane & 15, g = lane >> 4;
  const int ob = wave * 48;

  bf16x4 afr[3][8];
  #pragma unroll
  for (int mt = 0; mt < 3; ++mt)
    #pragma unroll
    for (int ks = 0; ks < 8; ++ks)
      afr[mt][ks] = *(const bf16x4*)&wqb[(ob + mt*16 + tl)*C_ + ks*16 + g*4];

  const f32x4 zero = {0.f,0.f,0.f,0.f};
  f32x4 acc[3][5];
  #pragma unroll
  for (int mt = 0; mt < 3; ++mt)
    #pragma unroll
    for (int nt = 0; nt < 5; ++nt) acc[mt][nt] = zero;

  #pragma unroll
  for (int ks = 0; ks < 8; ++ks) {
    bf16x4 bfr[5];
    #pragma unroll
    for (int nt = 0; nt < 5; ++nt)
      bfr[nt] = *(const bf16x4*)&xs[nt*16 + tl][ks*16 + g*4];
    #pragma unroll
    for (int mt = 0; mt < 3; ++mt)
      #pragma unroll
      for (int nt = 0; nt < 5; ++nt)
        acc[mt][nt] = mfma16(afr[mt][ks], bfr[nt], acc[mt][nt]);
  }

  float bia[3][4], scm[3];
  #pragma unroll
  for (int mt = 0; mt < 3; ++mt) {
    scm[mt] = (ob + mt*16 < DK_) ? (0.5f*1.44269504f) : 1.f;
    #pragma unroll
    for (int r = 0; r < 4; ++r) bia[mt][r] = qkv_b[ob + mt*16 + g*4 + r];
  }

  #pragma unroll
  for (int nt = 0; nt < 5; ++nt) {
    int tg = t0 + nt*16 + tl;
    if (tg >= T_) continue;
    #pragma unroll
    for (int mt = 0; mt < 3; ++mt) {
      int o = ob + mt*16 + g*4;
      short* dst = &qkvb[((size_t)b*QO_ + o)*T_ + tg];
      #pragma unroll
      for (int r = 0; r < 4; ++r)
        dst[r*T_] = f2bf((acc[mt][nt][r] + bia[mt][r]) * scm[mt]);
    }
  }
}

// ---------------------------------------------------------------------------
// k_attn: R16 base with FUSED per-st pipeline: each st does QK-MFMA -> rel
// MFMAs -> exp2 -> pack -> PV/ones accumulate. Removes the c[10] (40-reg)
// live block; compiler picks pipelining depth -> lower reg pressure, higher
// occupancy. Math identical (pure reordering of independent st-tiles).
// ---------------------------------------------------------------------------
__global__ __launch_bounds__(256) void k_attn(
    const short* __restrict__ qkvb, const short* __restrict__ krbg,
    short* __restrict__ o2b)
{
  const int bh = blockIdx.x;          // 0..3199
  const int b  = bh >> 3, h = bh & 7;
  __shared__ short kbc[160*4];        // K[s][d<4]                (1280 B)
  __shared__ short qbc[160*4];        // Q[t][d<4] pre-scaled     (1280 B)
  __shared__ short ve[16][164];       // V^T[e][s]                (5248 B)
  __shared__ short krb[336*4];        // kr rows bf16x4, row m+16 (2688 B)
  const short* base = qkvb + (size_t)b*QO_*T_;
  const int tid = threadIdx.x;

  for (int i = tid; i < 640; i += 256) {      // K then Q: 2 s/t per uint
    int isq = i >= 320, r = i - isq*320;
    int d = r / 80, j = r - d*80, s = 2*j;
    unsigned u = 0;
    if (j < 75) u = *(const unsigned*)&base[((isq ? 0 : DK_) + h*4 + d)*T_ + s];
    short* dst = isq ? qbc : kbc;
    dst[s*4 + d] = (short)u;
    dst[(s+1)*4 + d] = (short)(u >> 16);
  }
  for (int i = tid; i < 1280; i += 256) {     // V^T: uint copy
    int e = i / 80, j = i % 80;
    unsigned u = 0;
    if (j < 75) u = *(const unsigned*)&base[(2*DK_ + h*16 + e)*T_ + 2*j];
    *(unsigned*)&ve[e][2*j] = u;
  }
  for (int i = tid; i < 672; i += 256)        // kr: uint copy of bf16 table
    *(unsigned*)&krb[2*i] = *(const unsigned*)&krbg[2*i];
  __syncthreads();

  const int wave = tid >> 6, lane = tid & 63;
  const int tl = lane & 15, g = lane >> 4, soff = g << 2;

  const bf16x4 zerob = {0, 0, 0, 0};
  const bf16x4 onesb = {(short)0x3F80, (short)0x3F80, (short)0x3F80, (short)0x3F80};
  const f32x4 zero = {0.f, 0.f, 0.f, 0.f};

  bf16x4 kfr[10], vfr[10];
  #pragma unroll
  for (int st = 0; st < 10; ++st) {
    kfr[st] = (g == 0) ? *(const bf16x4*)&kbc[(st*16 + tl)*4] : zerob;
    vfr[st] = *(const bf16x4*)&ve[tl][st*16 + soff];
  }

  const bool act = (g == (tl & 3));   // lane holds B' nonzeros only here
  const int kca = tl >> 2;            // ...and only in this K-chunk

  for (int tt = wave; tt < 10; tt += 4) {
    const int t0 = tt*16, tg = t0 + tl;
    union { unsigned u[2]; bf16x4 v; } bqu;
    bqu.v = *(const bf16x4*)&qbc[tg*4];       // q row (pre-scaled)
    const bf16x4 qfr = (g == 0) ? bqu.v : zerob;

    bf16x4 brel[4];
    #pragma unroll
    for (int kc = 0; kc < 4; ++kc)
      brel[kc] = (act && kc == kca) ? bqu.v : zerob;

    // A' gather base: row = (tl - g + 165 - t0) + st*16 - kc*4
    const bf16x4* krp = ((const bf16x4*)krb) + (tl - g + 165 - t0);

    f32x4 acc = zero, lacc = zero;
    #pragma unroll
    for (int st = 0; st < 10; ++st) {
      f32x4 c = mfma16(kfr[st], qfr, zero);
      #pragma unroll
      for (int kc = 0; kc < 4; ++kc)
        c = mfma16(krp[st*16 - kc*4], brel[kc], c);

      if (st == 9) {   // mask padded s rows (s = 144+soff+i >= 150)
        #pragma unroll
        for (int i = 0; i < 4; ++i)
          if (soff + i >= 6) c[i] = -3.0e38f;
      }

      float p0 = __builtin_exp2f(c[0]);
      float p1 = __builtin_exp2f(c[1]);
      float p2 = __builtin_exp2f(c[2]);
      float p3 = __builtin_exp2f(c[3]);
      union { unsigned u[2]; bf16x4 v; } pf;
      pf.u[0] = pktr(p0, p1); pf.u[1] = pktr(p2, p3);
      acc  = mfma16(vfr[st], pf.v, acc);
      lacc = mfma16(onesb, pf.v, lacc);       // denominator on MFMA pipe
    }
    const float inv = __builtin_amdgcn_rcpf(lacc[0]);

    if (tg < T_) {
      unsigned u0 = pk2(acc[0]*inv, acc[1]*inv);
      unsigned u1 = pk2(acc[2]*inv, acc[3]*inv);
      *(uint2*)&o2b[((size_t)b*T_ + tg)*DV_ + h*16 + soff] = make_uint2(u0, u1);
    }
  }
}

// ---------------------------------------------------------------------------
// k_proj: bf16 MFMA GEMM  projb[b][o][t] = bf16(sum_c wab[o][c]*o2b[b][t][c] + attn_b[o])
// ---------------------------------------------------------------------------
__global__ __launch_bounds__(256) void k_proj(
    const short* __restrict__ o2b, const short* __restrict__ wab,
    const float* __restrict__ attn_b, short* __restrict__ projb)
{
  const int b = blockIdx.x, t0 = blockIdx.y * 80;
  __shared__ short xs[80][136];
  for (int i = threadIdx.x; i < 80*16; i += 256) {
    int tt = i >> 4, ch = i & 15, t = t0 + tt;
    short8 vv = {0,0,0,0,0,0,0,0};
    if (t < T_) vv = *(const short8*)&o2b[((size_t)b*T_ + t)*DV_ + ch*8];
    *(short8*)&xs[tt][ch*8] = vv;
  }
  __syncthreads();
  const int wave = threadIdx.x >> 6, lane = threadIdx.x & 63;
  const int tl = lane & 15, g = lane >> 4;
  const int ob = wave * 32;

  bf16x4 afr[2][8];
  #pragma unroll
  for (int mt = 0; mt < 2; ++mt)
    #pragma unroll
    for (int ks = 0; ks < 8; ++ks)
      afr[mt][ks] = *(const bf16x4*)&wab[(ob + mt*16 + tl)*DV_ + ks*16 + g*4];

  const f32x4 zero = {0.f,0.f,0.f,0.f};
  f32x4 acc[2][5];
  #pragma unroll
  for (int mt = 0; mt < 2; ++mt)
    #pragma unroll
    for (int nt = 0; nt < 5; ++nt) acc[mt][nt] = zero;

  #pragma unroll
  for (int ks = 0; ks < 8; ++ks) {
    bf16x4 bfr[5];
    #pragma unroll
    for (int nt = 0; nt < 5; ++nt)
      bfr[nt] = *(const bf16x4*)&xs[nt*16 + tl][ks*16 + g*4];
    #pragma unroll
    for (int mt = 0; mt < 2; ++mt)
      #pragma unroll
      for (int nt = 0; nt < 5; ++nt)
        acc[mt][nt] = mfma16(afr[mt][ks], bfr[nt], acc[mt][nt]);
  }

  float bia[2][4];
  #pragma unroll
  for (int mt = 0; mt < 2; ++mt)
    #pragma unroll
    for (int r = 0; r < 4; ++r) bia[mt][r] = attn_b[ob + mt*16 + g*4 + r];

  #pragma unroll
  for (int nt = 0; nt < 5; ++nt) {
    int tg = t0 + nt*16 + tl;
    if (tg >= T_) continue;
    #pragma unroll
    for (int mt = 0; mt < 2; ++mt) {
      int o = ob + mt*16 + g*4;
      short* dst = &projb[((size_t)b*DV_ + o)*T_ + tg];
      #pragma unroll
      for (int r = 0; r < 4; ++r)
        dst[r*T_] = f2bf(acc[mt][nt][r] + bia[mt][r]);
    }
  }
}

// ---------------------------------------------------------------------------
// k_final: transpose projb[b][o][t] -> out[n][o][t][v], + residual + BN + ReLU
// staging loop vectorized to uint copies (t-pairs, 4B aligned)
// ---------------------------------------------------------------------------
__global__ __launch_bounds__(256) void k_final(
    const short* __restrict__ projb, const float* __restrict__ x,
    const float* __restrict__ bn_g, const float* __restrict__ bn_b,
    const float* __restrict__ bn_m, const float* __restrict__ bn_v,
    float* __restrict__ out)
{
  const int n = blockIdx.x, o = blockIdx.y;
  __shared__ short ls[V_*T_];
  for (int i = threadIdx.x; i < V_*75; i += 256) {
    int v = i / 75, j = i % 75;
    *(unsigned*)&ls[v*T_ + 2*j] =
        *(const unsigned*)&projb[((size_t)(n*V_ + v)*DV_ + o)*T_ + 2*j];
  }
  __syncthreads();
  const float sc = bn_g[o] * rsqrtf(bn_v[o] + EPS_);
  const float sh = bn_b[o] - bn_m[o]*sc;
  const size_t base = ((size_t)n*C_ + o)*(T_*V_);
  for (int j = threadIdx.x; j < T_*V_; j += 256) {
    int t = j / V_, v = j % V_;
    float pv = lo16((unsigned)(unsigned short)ls[v*T_ + t]);
    float r = (pv + x[base + j]) * sc + sh;
    out[base + j] = fmaxf(r, 0.f);
  }
}

// ---------------------------------------------------------------------------
extern "C" void kernel_launch(void* const* d_in, const int* in_sizes, int n_in,
                              void* d_out, int out_size, void* d_ws, size_t ws_size,
                              hipStream_t stream) {
  const float* x       = (const float*)d_in[0];
  const float* qkv_w   = (const float*)d_in[1];
  const float* qkv_b   = (const float*)d_in[2];
  const float* key_rel = (const float*)d_in[3];
  const float* attn_w  = (const float*)d_in[4];
  const float* attn_b  = (const float*)d_in[5];
  const float* dbn_g   = (const float*)d_in[6];
  const float* dbn_b   = (const float*)d_in[7];
  const float* dbn_m   = (const float*)d_in[8];
  const float* dbn_v   = (const float*)d_in[9];
  const float* bn_g    = (const float*)d_in[10];
  const float* bn_b    = (const float*)d_in[11];
  const float* bn_m    = (const float*)d_in[12];
  const float* bn_v    = (const float*)d_in[13];

  // ws layout: xtb/o2b | qkvb | proj region (bf16 uses half) | consts
  short* xtb  = (short*)d_ws;                          // 7.68M shorts, reused as o2b
  short* o2b  = xtb;
  short* qkvb = xtb + (size_t)B_*C_*T_;                // 11.52M shorts
  float* projf = (float*)(qkvb + (size_t)B_*QO_*T_);   // region reserved as before
  short* projb = (short*)projf;                        // bf16 actually used
  float* dsc  = projf + (size_t)B_*DV_*T_;             // 3200
  float* dsh  = dsc + C_*V_;                           // 3200
  short* wqb  = (short*)(dsh + C_*V_);                 // 24576 shorts
  short* wab  = wqb + QO_*C_;                          // 16384 shorts
  short* krbg = wab + DV_*DV_;                         // 1344 shorts (bf16 kr)
  float* outp = (float*)d_out;

  k_prep<<<32, 256, 0, stream>>>(qkv_w, attn_w, dbn_g, dbn_b, dbn_m, dbn_v,
                                 key_rel, wqb, wab, krbg, dsc, dsh);
  k_xt2<<<dim3(N_, 30), 256, 0, stream>>>(x, dsc, dsh, xtb);
  k_qkv<<<dim3(B_, 2), 256, 0, stream>>>(xtb, wqb, qkv_b, qkvb);
  k_attn<<<dim3(B_*NH_), 256, 0, stream>>>(qkvb, krbg, o2b);
  k_proj<<<dim3(B_, 2), 256, 0, stream>>>(o2b, wab, attn_b, projb);
  k_final<<<dim3(N_, DV_), 256, 0, stream>>>(projb, x, bn_g, bn_b, bn_m, bn_v, outp);
}